// Round 3
// baseline (358.583 us; speedup 1.0000x reference)
//
#include <hip/hip_runtime.h>
#include <stdint.h>

#define NSPEC 16
#define IN_DIM 256
#define HID 512
#define ODIM 1024
#define NA 512
#define NB 32
#define NROWS (NA*NB)
#define NSLOTS 144

typedef __bf16 bf16x8 __attribute__((ext_vector_type(8)));
typedef float f32x4 __attribute__((ext_vector_type(4)));

// async global->LDS, 16B per lane. LDS dest wave-uniform base; HW adds lane*16.
#define GLOAD16(g, l) __builtin_amdgcn_global_load_lds( \
    (const __attribute__((address_space(1))) void*)(g), \
    (__attribute__((address_space(3))) void*)(l), 16, 0, 0)

__device__ __forceinline__ uint32_t f2bf1(float f){
  uint32_t u = __builtin_bit_cast(uint32_t, f);
  u += 0x7FFFu + ((u >> 16) & 1u);   // RNE
  return u >> 16;
}
__device__ __forceinline__ uint32_t pack2(float a, float b){
  return f2bf1(a) | (f2bf1(b) << 16);
}
__device__ __forceinline__ uint4 load8_pack(const float* __restrict__ src){
  float4 f0 = *reinterpret_cast<const float4*>(src);
  float4 f1 = *reinterpret_cast<const float4*>(src + 4);
  uint4 v;
  v.x = pack2(f0.x, f0.y); v.y = pack2(f0.z, f0.w);
  v.z = pack2(f1.x, f1.y); v.w = pack2(f1.z, f1.w);
  return v;
}
__device__ __forceinline__ float sigm(float x){ return 1.0f / (1.0f + __expf(-x)); }

// ---------------- prep: group a-indices by species into slots of <=4 ----------------
__global__ void k_prep(const int* __restrict__ sp, int* __restrict__ order,
                       int* __restrict__ slot_s, int* __restrict__ slot_st,
                       int* __restrict__ slot_na){
  __shared__ int cnt[NSPEC], off[NSPEC], cur[NSPEC];
  int t = threadIdx.x;
  if (t < NSPEC) cnt[t] = 0;
  __syncthreads();
  int s = sp[t];
  atomicAdd(&cnt[s], 1);
  __syncthreads();
  if (t == 0){
    int o = 0;
    for (int i = 0; i < NSPEC; i++){ off[i] = o; cur[i] = o; o += cnt[i]; }
  }
  __syncthreads();
  int pos = atomicAdd(&cur[s], 1);
  order[pos] = t;
  __syncthreads();
  if (t == 0){
    int k = 0;
    for (int i = 0; i < NSPEC; i++){
      int c = cnt[i], st = off[i];
      for (int j = 0; j < c; j += 4){
        slot_s[k] = i; slot_st[k] = st + j;
        slot_na[k] = (c - j < 4) ? (c - j) : 4; k++;
      }
    }
    for (; k < NSLOTS; k++){ slot_s[k] = 0; slot_st[k] = 0; slot_na[k] = 0; }
  }
}

// ---------------- conv: all fp32 operands -> bf16, pre-swizzled (+x permuted to slot order) ----------------
__global__ __launch_bounds__(256) void k_conv(
    const float* __restrict__ x, const float* __restrict__ w_in,
    const float* __restrict__ w_ih, const float* __restrict__ w_out,
    const int* __restrict__ order, const int* __restrict__ slot_st,
    const int* __restrict__ slot_na,
    ushort* __restrict__ xbf, ushort* __restrict__ wi,
    ushort* __restrict__ wg, ushort* __restrict__ wo)
{
  const int UX  = NSLOTS*128*(IN_DIM/8);   // 589824
  const int UWI = NSPEC*HID*(IN_DIM/8);    // 262144
  const int UWG = 3*HID*(HID/8);           // 98304
  const int UWO = NSPEC*ODIM*(HID/8);      // 1048576
  int total = UX + UWI + UWG + UWO;
  for (int u = blockIdx.x*256 + threadIdx.x; u < total; u += gridDim.x*256){
    uint4 v = {0u,0u,0u,0u};
    ushort* dst;
    if (u < UX){                                        // x: gather+permute+pad, 256-col rows
      int row = u >> 5, cu = u & 31;                    // row = slot*128 + r
      int s = row >> 7, r = row & 127;
      int cup = (cu & 24) | ((cu & 7) ^ (r & 7));
      dst = xbf + ((size_t)row << 8) + (cup << 3);
      if (r < slot_na[s]*32){
        int arow = order[slot_st[s] + (r >> 5)];
        v = load8_pack(x + ((size_t)(arow*NB + (r & 31)) << 8) + (cu << 3));
      }
    } else if (u < UX + UWI){                           // w_in: 256-col rows
      int t2 = u - UX; int row = t2 >> 5, cu = t2 & 31;
      int cup = (cu & 24) | ((cu & 7) ^ (row & 7));
      dst = wi + ((size_t)row << 8) + (cup << 3);
      v = load8_pack(w_in + ((size_t)row << 8) + (cu << 3));
    } else if (u < UX + UWI + UWG){                     // w_ih gates i,g,o: 512-col rows
      int t2 = u - UX - UWI; int row = t2 >> 6, cu = t2 & 63;
      int g = row >> 9;
      int srow = (g == 0 ? 0 : (g == 1 ? 1024 : 1536)) + (row & 511);
      int cup = (cu & 56) | ((cu & 7) ^ (row & 7));
      dst = wg + ((size_t)row << 9) + (cup << 3);
      v = load8_pack(w_ih + ((size_t)srow << 9) + (cu << 3));
    } else {                                            // w_out: 512-col rows
      int t2 = u - UX - UWI - UWG; int row = t2 >> 6, cu = t2 & 63;
      int cup = (cu & 56) | ((cu & 7) ^ (row & 7));
      dst = wo + ((size_t)row << 9) + (cup << 3);
      v = load8_pack(w_out + ((size_t)row << 9) + (cu << 3));
    }
    *reinterpret_cast<uint4*>(dst) = v;
  }
}

// ---------------- stage 1: xproj = relu(xbf @ wi[s]^T + b_in[s]) -> bf16 swz, slot-row order ----------------
// 1D grid 288 (xcd-swizzled): bx in {0,1} (BN=256), slot in 0..143. 512 threads.
__global__ __launch_bounds__(512) void k_xproj(
    const ushort* __restrict__ xbf, const ushort* __restrict__ wi,
    const float* __restrict__ b_in,
    const int* __restrict__ slot_s, const int* __restrict__ slot_na,
    ushort* __restrict__ xproj)
{
  int id = blockIdx.x;
  int swz = (id & 7)*36 + (id >> 3);       // 288 = 8*36, bijective
  int bx = swz & 1, slot = swz >> 1;
  int na = slot_na[slot];
  if (na == 0) return;
  int spec = slot_s[slot];
  int n0 = bx << 8;
  int tid = threadIdx.x, lane = tid & 63, wid = tid >> 6;
  int mh = wid >> 2, nh = wid & 3;
  int lr = lane & 15, lq = lane >> 4;

  __shared__ uint4 ldsA[128*8];   // 16KB: 128 x 64 bf16
  __shared__ uint4 ldsB[256*8];   // 32KB: 256 x 64 bf16

  f32x4 acc[4][4];
#pragma unroll
  for (int i = 0; i < 4; i++)
#pragma unroll
    for (int j = 0; j < 4; j++) acc[i][j] = (f32x4){0.f,0.f,0.f,0.f};

  for (int ch = 0; ch < 4; ++ch){
    int k0 = ch * 64;
#pragma unroll
    for (int i = 0; i < 2; i++){
      int u = i*512 + tid; int row = u >> 3, seg = u & 7;
      GLOAD16(xbf + (size_t)(slot*128 + row)*IN_DIM + k0 + seg*8, &ldsA[i*512 + wid*64]);
    }
#pragma unroll
    for (int i = 0; i < 4; i++){
      int u = i*512 + tid; int row = u >> 3, seg = u & 7;
      GLOAD16(wi + (size_t)(spec*HID + n0 + row)*IN_DIM + k0 + seg*8, &ldsB[i*512 + wid*64]);
    }
    __syncthreads();
#pragma unroll
    for (int kk = 0; kk < 2; ++kk){
      int lk = lq + kk*4;
      bf16x8 af[4], bfr[4];
#pragma unroll
      for (int mt = 0; mt < 4; mt++){
        int r = mh*64 + mt*16 + lr;
        af[mt] = __builtin_bit_cast(bf16x8, ldsA[r*8 + (lk ^ (r & 7))]);
      }
#pragma unroll
      for (int nt = 0; nt < 4; nt++){
        int r = nh*64 + nt*16 + lr;
        bfr[nt] = __builtin_bit_cast(bf16x8, ldsB[r*8 + (lk ^ (r & 7))]);
      }
#pragma unroll
      for (int mt = 0; mt < 4; mt++)
#pragma unroll
        for (int nt = 0; nt < 4; nt++)
          acc[mt][nt] = __builtin_amdgcn_mfma_f32_16x16x32_bf16(af[mt], bfr[nt], acc[mt][nt], 0, 0, 0);
    }
    __syncthreads();
  }
#pragma unroll
  for (int mt = 0; mt < 4; mt++){
#pragma unroll
    for (int j = 0; j < 4; j++){
      int prl = mh*64 + mt*16 + lq*4 + j;
#pragma unroll
      for (int nt = 0; nt < 4; nt++){
        int col = n0 + nh*64 + nt*16 + lr;
        float v = acc[mt][nt][j] + b_in[spec*HID + col];
        v = v > 0.f ? v : 0.f;
        int colp = (col & ~63) | ((((col >> 3) & 7) ^ (prl & 7)) << 3) | (col & 7);
        xproj[(size_t)(slot*128 + prl)*HID + colp] = (ushort)f2bf1(v);
      }
    }
  }
}

// ---------------- stage 2: gates i,g,o + LSTM cell -> hout,cout (fp32, scattered) + h1bf (bf16 swz) ----------------
// 1D grid 576: bx in 0..3 (gate-BN=128), slot 0..143. 512 threads.
__global__ __launch_bounds__(512) void k_lstm(
    const ushort* __restrict__ xproj, const ushort* __restrict__ wg,
    const float* __restrict__ b_ih, const float* __restrict__ b_hh,
    const int* __restrict__ order, const int* __restrict__ slot_st,
    const int* __restrict__ slot_na,
    float* __restrict__ hout, float* __restrict__ cout_,
    ushort* __restrict__ h1bf)
{
  int id = blockIdx.x;
  int swz = (id & 7)*72 + (id >> 3);       // 576 = 8*72, bijective
  int bx = swz & 3, slot = swz >> 2;
  int na = slot_na[slot];
  if (na == 0) return;
  int st = slot_st[slot];
  int n0 = bx << 7;
  int tid = threadIdx.x, lane = tid & 63, wid = tid >> 6;
  int mh = wid >> 2, nh = wid & 3;
  int lr = lane & 15, lq = lane >> 4;

  int arow[4];
#pragma unroll
  for (int i = 0; i < 4; i++) arow[i] = (i < na) ? order[st + i] : 0;

  __shared__ uint4 ldsA[128*8];   // 16KB
  __shared__ uint4 ldsB[384*8];   // 48KB: 3 gates x 128 x 64

  f32x4 acc[4][6];
#pragma unroll
  for (int i = 0; i < 4; i++)
#pragma unroll
    for (int j = 0; j < 6; j++) acc[i][j] = (f32x4){0.f,0.f,0.f,0.f};

  for (int ch = 0; ch < 8; ++ch){
    int k0 = ch * 64;
#pragma unroll
    for (int i = 0; i < 2; i++){
      int u = i*512 + tid; int row = u >> 3, seg = u & 7;
      GLOAD16(xproj + (size_t)(slot*128 + row)*HID + k0 + seg*8, &ldsA[i*512 + wid*64]);
    }
#pragma unroll
    for (int i = 0; i < 6; i++){
      int u = i*512 + tid; int rr = u >> 3, seg = u & 7;
      int g = rr >> 7;
      GLOAD16(wg + (size_t)(g*HID + n0 + (rr & 127))*HID + k0 + seg*8, &ldsB[i*512 + wid*64]);
    }
    __syncthreads();
#pragma unroll
    for (int kk = 0; kk < 2; ++kk){
      int lk = lq + kk*4;
      bf16x8 af[4], bfr[6];
#pragma unroll
      for (int mt = 0; mt < 4; mt++){
        int r = mh*64 + mt*16 + lr;
        af[mt] = __builtin_bit_cast(bf16x8, ldsA[r*8 + (lk ^ (r & 7))]);
      }
#pragma unroll
      for (int g = 0; g < 3; g++)
#pragma unroll
        for (int t = 0; t < 2; t++){
          int rr = g*128 + nh*32 + t*16 + lr;
          bfr[g*2 + t] = __builtin_bit_cast(bf16x8, ldsB[rr*8 + (lk ^ (rr & 7))]);
        }
#pragma unroll
      for (int mt = 0; mt < 4; mt++)
#pragma unroll
        for (int gn = 0; gn < 6; gn++)
          acc[mt][gn] = __builtin_amdgcn_mfma_f32_16x16x32_bf16(af[mt], bfr[gn], acc[mt][gn], 0, 0, 0);
    }
    __syncthreads();
  }
#pragma unroll
  for (int t = 0; t < 2; t++){
    int c = n0 + nh*32 + t*16 + lr;          // h-column 0..511
    float bi0 = b_ih[c]        + b_hh[c];
    float bi1 = b_ih[1024 + c] + b_hh[1024 + c];
    float bi2 = b_ih[1536 + c] + b_hh[1536 + c];
#pragma unroll
    for (int mt = 0; mt < 4; mt++){
#pragma unroll
      for (int j = 0; j < 4; j++){
        int prl = mh*64 + mt*16 + lq*4 + j;
        float gi = acc[mt][0 + t][j] + bi0;
        float gg = acc[mt][2 + t][j] + bi1;
        float go = acc[mt][4 + t][j] + bi2;
        float iv = sigm(gi);
        float gv = tanhf(gg);
        float ov = sigm(go);
        float c1 = iv * gv;
        float h1 = ov * tanhf(c1);
        int colp = (c & ~63) | ((((c >> 3) & 7) ^ (prl & 7)) << 3) | (c & 7);
        h1bf[(size_t)(slot*128 + prl)*HID + colp] = (ushort)f2bf1(h1);
        if (prl < na*32){
          size_t grow = (size_t)(arow[prl >> 5]*NB + (prl & 31));
          hout[grow*HID + c] = h1;
          cout_[grow*HID + c] = c1;
        }
      }
    }
  }
}

// ---------------- stage 3: logits = h1bf @ wo[s]^T + b_out[s] (fp32, scattered rows) ----------------
// 1D grid 576: bx in 0..3 (BN=256), slot 0..143. 512 threads.
__global__ __launch_bounds__(512) void k_logits(
    const ushort* __restrict__ h1bf, const ushort* __restrict__ wo,
    const float* __restrict__ b_out,
    const int* __restrict__ order, const int* __restrict__ slot_s,
    const int* __restrict__ slot_st, const int* __restrict__ slot_na,
    float* __restrict__ logits)
{
  int id = blockIdx.x;
  int swz = (id & 7)*72 + (id >> 3);
  int bx = swz & 3, slot = swz >> 2;
  int na = slot_na[slot];
  if (na == 0) return;
  int spec = slot_s[slot];
  int st = slot_st[slot];
  int n0 = bx << 8;
  int tid = threadIdx.x, lane = tid & 63, wid = tid >> 6;
  int mh = wid >> 2, nh = wid & 3;
  int lr = lane & 15, lq = lane >> 4;

  int arow[4];
#pragma unroll
  for (int i = 0; i < 4; i++) arow[i] = (i < na) ? order[st + i] : 0;

  __shared__ uint4 ldsA[128*8];   // 16KB
  __shared__ uint4 ldsB[256*8];   // 32KB

  f32x4 acc[4][4];
#pragma unroll
  for (int i = 0; i < 4; i++)
#pragma unroll
    for (int j = 0; j < 4; j++) acc[i][j] = (f32x4){0.f,0.f,0.f,0.f};

  for (int ch = 0; ch < 8; ++ch){
    int k0 = ch * 64;
#pragma unroll
    for (int i = 0; i < 2; i++){
      int u = i*512 + tid; int row = u >> 3, seg = u & 7;
      GLOAD16(h1bf + (size_t)(slot*128 + row)*HID + k0 + seg*8, &ldsA[i*512 + wid*64]);
    }
#pragma unroll
    for (int i = 0; i < 4; i++){
      int u = i*512 + tid; int rr = u >> 3, seg = u & 7;
      GLOAD16(wo + (size_t)(spec*ODIM + n0 + rr)*HID + k0 + seg*8, &ldsB[i*512 + wid*64]);
    }
    __syncthreads();
#pragma unroll
    for (int kk = 0; kk < 2; ++kk){
      int lk = lq + kk*4;
      bf16x8 af[4], bfr[4];
#pragma unroll
      for (int mt = 0; mt < 4; mt++){
        int r = mh*64 + mt*16 + lr;
        af[mt] = __builtin_bit_cast(bf16x8, ldsA[r*8 + (lk ^ (r & 7))]);
      }
#pragma unroll
      for (int nt = 0; nt < 4; nt++){
        int r = nh*64 + nt*16 + lr;
        bfr[nt] = __builtin_bit_cast(bf16x8, ldsB[r*8 + (lk ^ (r & 7))]);
      }
#pragma unroll
      for (int mt = 0; mt < 4; mt++)
#pragma unroll
        for (int nt = 0; nt < 4; nt++)
          acc[mt][nt] = __builtin_amdgcn_mfma_f32_16x16x32_bf16(af[mt], bfr[nt], acc[mt][nt], 0, 0, 0);
    }
    __syncthreads();
  }
#pragma unroll
  for (int mt = 0; mt < 4; mt++){
#pragma unroll
    for (int j = 0; j < 4; j++){
      int prl = mh*64 + mt*16 + lq*4 + j;
      if (prl >= na*32) continue;
      size_t grow = (size_t)(arow[prl >> 5]*NB + (prl & 31));
#pragma unroll
      for (int nt = 0; nt < 4; nt++){
        int col = n0 + nh*64 + nt*16 + lr;
        logits[grow*ODIM + col] = acc[mt][nt][j] + b_out[spec*ODIM + col];
      }
    }
  }
}

extern "C" void kernel_launch(void* const* d_in, const int* in_sizes, int n_in,
                              void* d_out, int out_size, void* d_ws, size_t ws_size,
                              hipStream_t stream){
  const float* x     = (const float*)d_in[0];
  const int*   sp    = (const int*)  d_in[1];
  const float* w_in  = (const float*)d_in[2];
  const float* b_in  = (const float*)d_in[3];
  const float* w_ih  = (const float*)d_in[4];
  // d_in[5] = w_hh: unused (h0 == 0)
  const float* b_ih  = (const float*)d_in[6];
  const float* b_hh  = (const float*)d_in[7];
  const float* w_out = (const float*)d_in[8];
  const float* b_out = (const float*)d_in[9];

  float* out    = (float*)d_out;
  float* logits = out;                                   // 16384*1024 f32
  float* hout   = out + (size_t)NROWS * ODIM;            // 16384*512 f32
  float* cout_  = hout + (size_t)NROWS * HID;            // 16384*512 f32

  // d_ws layout (ws_size = 512 MiB; we use ~70 MB)
  int* order   = (int*)d_ws;                 // 512
  int* slot_s  = order + NA;                 // 144
  int* slot_st = slot_s + NSLOTS;            // 144
  int* slot_na = slot_st + NSLOTS;           // 144  (3776 B < 4096)
  ushort* xbf   = (ushort*)((char*)d_ws + 4096);             // 144*128*256  = 9.4 MB
  ushort* xproj = xbf   + (size_t)NSLOTS*128*IN_DIM;         // 144*128*512  = 18.9 MB
  ushort* h1bf  = xproj + (size_t)NSLOTS*128*HID;            // 18.9 MB
  ushort* wi    = h1bf  + (size_t)NSLOTS*128*HID;            // 4 MB
  ushort* wg    = wi    + (size_t)NSPEC*HID*IN_DIM;          // 1.5 MB
  ushort* wo    = wg    + (size_t)3*HID*HID;                 // 16 MB

  k_prep<<<1, NA, 0, stream>>>(sp, order, slot_s, slot_st, slot_na);
  k_conv<<<1024, 256, 0, stream>>>(x, w_in, w_ih, w_out, order, slot_st, slot_na,
                                   xbf, wi, wg, wo);
  k_xproj<<<288, 512, 0, stream>>>(xbf, wi, b_in, slot_s, slot_na, xproj);
  k_lstm<<<576, 512, 0, stream>>>(xproj, wg, b_ih, b_hh, order, slot_st, slot_na,
                                  hout, cout_, h1bf);
  k_logits<<<576, 512, 0, stream>>>(h1bf, wo, b_out, order, slot_s, slot_st, slot_na, logits);
}